// Round 4
// baseline (66220.215 us; speedup 1.0000x reference)
//
#include <hip/hip_runtime.h>

// Persistent-LSTM MI355X — Round 4: data-driven sync (no barrier counters).
// R3 diagnosis: 4.57us/step = ~0.7us VALU + ~3.9us barrier chain; the leaf
// atomic_fetch_add (32 same-line RMWs/leaf/step, serialized at L3) dominated.
// R4: publish each hidden unit as ONE 8B atomic {tag=step | h bits}; consumers
// poll the data itself for tag==t. Equality check makes 0xAA poison inert (no
// reset phase). Parity ping-pong (buf0 even tags, buf1 odd) makes slot reuse
// race-free: writing tag t+2 requires having observed all tags t+1, which
// implies every block finished reading buf[t&1]. Sync chain: publish -> poll
// (the staging load IS the sync) = ~2 L3 RTTs/step.
//
// 256 blocks x 512 threads (8 waves), 1 block/CU (VGPR>128 -> 2 waves/SIMD
// max -> 1 block/CU -> all 256 blocks co-resident, spin-poll deadlock-free).
// Block b owns units [8b,8b+8); wave wv owns unit j=8b+wv (4 gate rows).
// Lane ln owns float4 chunks {ln+64k, k=0..7} of each 2048-wide row.

#define H      2048
#define TSTEPS 8192
#define FEAT   128
#define NBLK   256
#define NTHR   512

typedef float vf4 __attribute__((ext_vector_type(4)));
typedef float vf2 __attribute__((ext_vector_type(2)));
typedef unsigned long long u64;

__device__ __forceinline__ float sigm(float xv) {
  return __builtin_amdgcn_rcpf(1.0f + __expf(-xv));
}
__device__ __forceinline__ float tanh_(float xv) {
  return 1.0f - 2.0f * __builtin_amdgcn_rcpf(__expf(2.0f * xv) + 1.0f);
}

#define DECLG(g) vf4 w##g##_0, w##g##_1, w##g##_2, w##g##_3, \
                     w##g##_4, w##g##_5, w##g##_6, w##g##_7; \
                 vf2 wih##g; float bias##g; float acc##g;

#define LOADG(g) { \
  const int row_ = (g) * H + j; \
  const float* wr_ = W_hh + (long)row_ * H; \
  w##g##_0 = *(const vf4*)(wr_ + 4*(ln      )); \
  w##g##_1 = *(const vf4*)(wr_ + 4*(ln +  64)); \
  w##g##_2 = *(const vf4*)(wr_ + 4*(ln + 128)); \
  w##g##_3 = *(const vf4*)(wr_ + 4*(ln + 192)); \
  w##g##_4 = *(const vf4*)(wr_ + 4*(ln + 256)); \
  w##g##_5 = *(const vf4*)(wr_ + 4*(ln + 320)); \
  w##g##_6 = *(const vf4*)(wr_ + 4*(ln + 384)); \
  w##g##_7 = *(const vf4*)(wr_ + 4*(ln + 448)); \
  wih##g  = *(const vf2*)(W_ih + (long)row_ * FEAT + 2*ln); \
  bias##g = b_ih[row_] + b_hh[row_]; }

// Opaque pin: weight values become non-rematerializable (cannot be re-sunk
// into the loop as loads).
#define PIN(g) asm volatile("" : \
  "+v"(w##g##_0), "+v"(w##g##_1), "+v"(w##g##_2), "+v"(w##g##_3), \
  "+v"(w##g##_4), "+v"(w##g##_5), "+v"(w##g##_6), "+v"(w##g##_7), \
  "+v"(wih##g), "+v"(bias##g));

#define LDSREAD(k, ldsrow) \
  const vf4 hv##k = *(const vf4*)&(ldsrow)[4*(ln + 64*(k))];

#define FMA_G(g, c) \
  acc##g = __builtin_fmaf(w##g##_##c.x, h4_.x, acc##g); \
  acc##g = __builtin_fmaf(w##g##_##c.y, h4_.y, acc##g); \
  acc##g = __builtin_fmaf(w##g##_##c.z, h4_.z, acc##g); \
  acc##g = __builtin_fmaf(w##g##_##c.w, h4_.w, acc##g);

#define FMA_C(c) { const vf4 h4_ = hv##c; \
  FMA_G(0, c) FMA_G(1, c) FMA_G(2, c) FMA_G(3, c) }

#define REDUCE(g) { float a_ = acc##g; \
  a_ += __shfl_xor(a_, 1);  a_ += __shfl_xor(a_, 2);  a_ += __shfl_xor(a_, 4); \
  a_ += __shfl_xor(a_, 8);  a_ += __shfl_xor(a_, 16); a_ += __shfl_xor(a_, 32); \
  acc##g = a_ + bias##g; }

// Poll 2048 tagged pairs for tag==tg (lane ln owns pairs {ln+64k}), then
// deposit the 2048 h values into ldsrow. Executed by wave 0 only.
__device__ __forceinline__ void stage_poll(const u64* __restrict__ buf,
                                           unsigned tg,
                                           float* __restrict__ ldsrow,
                                           int ln) {
  u64 pv[32];
  #pragma unroll
  for (int k = 0; k < 32; ++k)
    pv[k] = __hip_atomic_load(buf + ln + 64 * k, __ATOMIC_RELAXED,
                              __HIP_MEMORY_SCOPE_AGENT);
  while (true) {
    int ok = 1;
    #pragma unroll
    for (int k = 0; k < 32; ++k)
      ok &= ((unsigned)pv[k] == tg) ? 1 : 0;
    if (__all(ok)) break;
    __builtin_amdgcn_s_sleep(1);
    #pragma unroll
    for (int k = 0; k < 32; ++k)
      if ((unsigned)pv[k] != tg)
        pv[k] = __hip_atomic_load(buf + ln + 64 * k, __ATOMIC_RELAXED,
                                  __HIP_MEMORY_SCOPE_AGENT);
  }
  #pragma unroll
  for (int k = 0; k < 32; ++k)
    ldsrow[ln + 64 * k] = __uint_as_float((unsigned)(pv[k] >> 32));
}

__global__ __launch_bounds__(NTHR, 2)
void lstm_persist(const float* __restrict__ x,
                  const float* __restrict__ W_ih,
                  const float* __restrict__ W_hh,
                  const float* __restrict__ b_ih,
                  const float* __restrict__ b_hh,
                  const float* __restrict__ W_lin,
                  const float* __restrict__ b_lin,
                  const float* __restrict__ W_out,
                  const float* __restrict__ b_out,
                  float* __restrict__ out,
                  float* __restrict__ ws)
{
  const int tid = threadIdx.x;
  const int b   = blockIdx.x;
  const int wv  = tid >> 6;
  const int ln  = tid & 63;

  u64* buf0 = (u64*)ws;        // pairs {tag|val} for even tags
  u64* buf1 = buf0 + H;        // pairs for odd tags

  __shared__ __align__(16) float h_lds[2][H];

  // h_0 = 0: zero LDS parity-0 row (512 threads x 16B = 8 KiB)
  *(vf4*)&h_lds[0][4 * tid] = (vf4)(0.0f);

  // ---- persistent weights: load then pin ----
  const int j = b * 8 + wv;     // this wave's hidden unit
  DECLG(0) DECLG(1) DECLG(2) DECLG(3)
  LOADG(0) LOADG(1) LOADG(2) LOADG(3)
  PIN(0) PIN(1) PIN(2) PIN(3)

  __syncthreads();   // LDS zero visible block-wide

  float cst = 0.0f;   // cell state of unit j (all lanes redundant)

  #pragma unroll 1
  for (int t = 0; t < TSTEPS; ++t) {
    const vf2 xr = *(const vf2*)(x + (long)t * FEAT + 2 * ln);
    float* ldsrow = h_lds[t & 1];

    if (t > 0 && wv == 0)
      stage_poll((t & 1) ? buf1 : buf0, (unsigned)t, ldsrow, ln);
    __syncthreads();

    LDSREAD(0, ldsrow) LDSREAD(1, ldsrow) LDSREAD(2, ldsrow) LDSREAD(3, ldsrow)
    LDSREAD(4, ldsrow) LDSREAD(5, ldsrow) LDSREAD(6, ldsrow) LDSREAD(7, ldsrow)

    acc0 = wih0.x * xr.x + wih0.y * xr.y;
    acc1 = wih1.x * xr.x + wih1.y * xr.y;
    acc2 = wih2.x * xr.x + wih2.y * xr.y;
    acc3 = wih3.x * xr.x + wih3.y * xr.y;

    FMA_C(0) FMA_C(1) FMA_C(2) FMA_C(3)
    FMA_C(4) FMA_C(5) FMA_C(6) FMA_C(7)

    REDUCE(0) REDUCE(1) REDUCE(2) REDUCE(3)

    // gate order [i, f, g, o]
    const float iv = sigm(acc0);
    const float fv = sigm(acc1);
    const float gv = tanh_(acc2);
    const float ov = sigm(acc3);
    cst = fv * cst + iv * gv;
    const float hval = ov * tanh_(cst);

    if (ln == 0) {
      u64* dst = (((t + 1) & 1) ? buf1 : buf0) + j;
      const u64 pack = ((u64)__float_as_uint(hval) << 32)
                     | (unsigned)(t + 1);
      __hip_atomic_store(dst, pack, __ATOMIC_RELAXED,
                         __HIP_MEMORY_SCOPE_AGENT);
    }
    // no trailing barrier: next iteration's syncthreads + parity ping-pong
    // provide all intra-block ordering; cross-block ordering is the tag.
  }

  // ---- head phase 1: ylin[j] = b_lin[j] + dot(W_lin[j,:], h_final) ----
  // h_final has tag TSTEPS (even) in buf0.
  {
    float* ldsrow = h_lds[0];
    if (wv == 0)
      stage_poll(buf0, (unsigned)TSTEPS, ldsrow, ln);
    __syncthreads();

    float a0 = 0.0f;
    const float* wl = W_lin + (long)j * H;
    #pragma unroll
    for (int k = 0; k < 8; ++k) {
      const vf4 h4 = *(const vf4*)&ldsrow[4 * (ln + 64 * k)];
      const vf4 u  = *(const vf4*)(wl + 4 * (ln + 64 * k));
      a0 += u.x * h4.x + u.y * h4.y + u.z * h4.z + u.w * h4.w;
    }
    a0 += __shfl_xor(a0, 1);  a0 += __shfl_xor(a0, 2);  a0 += __shfl_xor(a0, 4);
    a0 += __shfl_xor(a0, 8);  a0 += __shfl_xor(a0, 16); a0 += __shfl_xor(a0, 32);

    if (ln == 0) {
      const float yv = a0 + b_lin[j];
      const u64 pack = ((u64)__float_as_uint(yv) << 32)
                     | (unsigned)(TSTEPS + 1);
      __hip_atomic_store(buf1 + j, pack, __ATOMIC_RELAXED,
                         __HIP_MEMORY_SCOPE_AGENT);
    }
  }

  // ---- head phase 2: y = ylin @ W_out.T + b_out (block 0, wave 0) ----
  if (b == 0 && wv == 0) {
    u64 pv[32];
    #pragma unroll
    for (int k = 0; k < 32; ++k)
      pv[k] = __hip_atomic_load(buf1 + ln + 64 * k, __ATOMIC_RELAXED,
                                __HIP_MEMORY_SCOPE_AGENT);
    while (true) {
      int ok = 1;
      #pragma unroll
      for (int k = 0; k < 32; ++k)
        ok &= ((unsigned)pv[k] == (unsigned)(TSTEPS + 1)) ? 1 : 0;
      if (__all(ok)) break;
      __builtin_amdgcn_s_sleep(1);
      #pragma unroll
      for (int k = 0; k < 32; ++k)
        if ((unsigned)pv[k] != (unsigned)(TSTEPS + 1))
          pv[k] = __hip_atomic_load(buf1 + ln + 64 * k, __ATOMIC_RELAXED,
                                    __HIP_MEMORY_SCOPE_AGENT);
    }
    float p0 = 0.0f, p1 = 0.0f;
    #pragma unroll
    for (int k = 0; k < 32; ++k) {
      const int c = ln + 64 * k;
      const float yv = __uint_as_float((unsigned)(pv[k] >> 32));
      p0 = __builtin_fmaf(W_out[c],     yv, p0);
      p1 = __builtin_fmaf(W_out[H + c], yv, p1);
    }
    p0 += __shfl_xor(p0, 1);  p0 += __shfl_xor(p0, 2);  p0 += __shfl_xor(p0, 4);
    p0 += __shfl_xor(p0, 8);  p0 += __shfl_xor(p0, 16); p0 += __shfl_xor(p0, 32);
    p1 += __shfl_xor(p1, 1);  p1 += __shfl_xor(p1, 2);  p1 += __shfl_xor(p1, 4);
    p1 += __shfl_xor(p1, 8);  p1 += __shfl_xor(p1, 16); p1 += __shfl_xor(p1, 32);
    if (ln == 0) {
      out[0] = p0 + b_out[0];
      out[1] = p1 + b_out[1];
    }
  }
}

extern "C" void kernel_launch(void* const* d_in, const int* in_sizes, int n_in,
                              void* d_out, int out_size, void* d_ws, size_t ws_size,
                              hipStream_t stream) {
  const float* x     = (const float*)d_in[0];
  const float* W_ih  = (const float*)d_in[1];
  const float* W_hh  = (const float*)d_in[2];
  const float* b_ih  = (const float*)d_in[3];
  const float* b_hh  = (const float*)d_in[4];
  const float* W_lin = (const float*)d_in[5];
  const float* b_lin = (const float*)d_in[6];
  const float* W_out = (const float*)d_in[7];
  const float* b_out = (const float*)d_in[8];

  lstm_persist<<<dim3(NBLK), dim3(NTHR), 0, stream>>>(
      x, W_ih, W_hh, b_ih, b_hh, W_lin, b_lin, W_out, b_out,
      (float*)d_out, (float*)d_ws);
}

// Round 5
// 45944.424 us; speedup vs baseline: 1.4413x; 1.4413x over previous
//
#include <hip/hip_runtime.h>

// Persistent-LSTM MI355X — Round 5: distributed speculative staging.
// R4 regression diagnosis: wave0-only poll of all 2048 tagged pairs (32
// loads/lane, vmcnt(0) per round, retried) = polling storm; FETCH 354MB->2.4GB,
// round latency ~1-2us under 256-block MSHR contention -> 8us/step.
// R5: keep the self-validating {tag|val} pair protocol (no RMW, no fence,
// poison-inert, parity ping-pong safe — proven correct in R4), but split the
// staging across ALL 8 waves: wave wv owns pairs [wv*256, wv*256+256), 4
// pairs/lane (32B). The one-shot data read IS the poll; each wave re-loads
// only its stale entries. Poll round = 4 loads/lane instead of 32, x8 waves
// in parallel -> detect+stage ~1us instead of ~6us.
//
// 256 blocks x 512 threads (8 waves), 1 block/CU co-residency guaranteed
// (grid=256 <= capacity at VGPR<=256), spin-poll deadlock-free (see parity
// argument below). Block b owns units [8b,8b+8); wave wv computes unit
// j=8b+wv (4 gate rows j, H+j, 2H+j, 3H+j); lane ln owns h-chunks {ln+64k}.
//
// Reuse safety: block b writes tag t+2 into buf[p] slot j only after all its
// waves verified ALL 2048 tags==t+1 (syncthreads join before compute), and
// any block's t+1 publish is ordered after it finished reading buf[p]@t.

#define H      2048
#define TSTEPS 8192
#define FEAT   128
#define NBLK   256
#define NTHR   512

typedef float vf4 __attribute__((ext_vector_type(4)));
typedef float vf2 __attribute__((ext_vector_type(2)));
typedef unsigned long long u64;

__device__ __forceinline__ float sigm(float xv) {
  return __builtin_amdgcn_rcpf(1.0f + __expf(-xv));
}
__device__ __forceinline__ float tanh_(float xv) {
  return 1.0f - 2.0f * __builtin_amdgcn_rcpf(__expf(2.0f * xv) + 1.0f);
}

#define DECLG(g) vf4 w##g##_0, w##g##_1, w##g##_2, w##g##_3, \
                     w##g##_4, w##g##_5, w##g##_6, w##g##_7; \
                 vf2 wih##g; float bias##g; float acc##g;

#define LOADG(g) { \
  const int row_ = (g) * H + j; \
  const float* wr_ = W_hh + (long)row_ * H; \
  w##g##_0 = *(const vf4*)(wr_ + 4*(ln      )); \
  w##g##_1 = *(const vf4*)(wr_ + 4*(ln +  64)); \
  w##g##_2 = *(const vf4*)(wr_ + 4*(ln + 128)); \
  w##g##_3 = *(const vf4*)(wr_ + 4*(ln + 192)); \
  w##g##_4 = *(const vf4*)(wr_ + 4*(ln + 256)); \
  w##g##_5 = *(const vf4*)(wr_ + 4*(ln + 320)); \
  w##g##_6 = *(const vf4*)(wr_ + 4*(ln + 384)); \
  w##g##_7 = *(const vf4*)(wr_ + 4*(ln + 448)); \
  wih##g  = *(const vf2*)(W_ih + (long)row_ * FEAT + 2*ln); \
  bias##g = b_ih[row_] + b_hh[row_]; }

// Opaque pin: weights become non-rematerializable (cannot re-sink into loop).
#define PIN(g) asm volatile("" : \
  "+v"(w##g##_0), "+v"(w##g##_1), "+v"(w##g##_2), "+v"(w##g##_3), \
  "+v"(w##g##_4), "+v"(w##g##_5), "+v"(w##g##_6), "+v"(w##g##_7), \
  "+v"(wih##g), "+v"(bias##g));

#define LDSREAD(k, ldsrow) \
  const vf4 hv##k = *(const vf4*)&(ldsrow)[4*(ln + 64*(k))];

#define FMA_G(g, c) \
  acc##g = __builtin_fmaf(w##g##_##c.x, h4_.x, acc##g); \
  acc##g = __builtin_fmaf(w##g##_##c.y, h4_.y, acc##g); \
  acc##g = __builtin_fmaf(w##g##_##c.z, h4_.z, acc##g); \
  acc##g = __builtin_fmaf(w##g##_##c.w, h4_.w, acc##g);

#define FMA_C(c) { const vf4 h4_ = hv##c; \
  FMA_G(0, c) FMA_G(1, c) FMA_G(2, c) FMA_G(3, c) }

#define REDUCE(g) { float a_ = acc##g; \
  a_ += __shfl_xor(a_, 1);  a_ += __shfl_xor(a_, 2);  a_ += __shfl_xor(a_, 4); \
  a_ += __shfl_xor(a_, 8);  a_ += __shfl_xor(a_, 16); a_ += __shfl_xor(a_, 32); \
  acc##g = a_ + bias##g; }

__device__ __forceinline__ u64 aload(const u64* p) {
  return __hip_atomic_load(p, __ATOMIC_RELAXED, __HIP_MEMORY_SCOPE_AGENT);
}

// Per-wave slice stage: wave wv polls+reads pairs [wv*256, wv*256+256),
// 4 pairs per lane (contiguous 32B), deposits values into ldsrow.
__device__ __forceinline__ void stage_slice(const u64* __restrict__ buf,
                                            unsigned tg,
                                            float* __restrict__ ldsrow,
                                            int wv, int ln) {
  const int base = wv * 256 + ln * 4;
  const u64* p = buf + base;
  u64 a0 = aload(p + 0), a1 = aload(p + 1);
  u64 a2 = aload(p + 2), a3 = aload(p + 3);
  while (true) {
    const int ok = ((unsigned)a0 == tg) & ((unsigned)a1 == tg) &
                   ((unsigned)a2 == tg) & ((unsigned)a3 == tg);
    if (__all(ok)) break;
    __builtin_amdgcn_s_sleep(1);
    if ((unsigned)a0 != tg) a0 = aload(p + 0);
    if ((unsigned)a1 != tg) a1 = aload(p + 1);
    if ((unsigned)a2 != tg) a2 = aload(p + 2);
    if ((unsigned)a3 != tg) a3 = aload(p + 3);
  }
  vf4 hv;
  hv.x = __uint_as_float((unsigned)(a0 >> 32));
  hv.y = __uint_as_float((unsigned)(a1 >> 32));
  hv.z = __uint_as_float((unsigned)(a2 >> 32));
  hv.w = __uint_as_float((unsigned)(a3 >> 32));
  *(vf4*)&ldsrow[base] = hv;
}

__global__ __launch_bounds__(NTHR, 2)
void lstm_persist(const float* __restrict__ x,
                  const float* __restrict__ W_ih,
                  const float* __restrict__ W_hh,
                  const float* __restrict__ b_ih,
                  const float* __restrict__ b_hh,
                  const float* __restrict__ W_lin,
                  const float* __restrict__ b_lin,
                  const float* __restrict__ W_out,
                  const float* __restrict__ b_out,
                  float* __restrict__ out,
                  float* __restrict__ ws)
{
  const int tid = threadIdx.x;
  const int b   = blockIdx.x;
  const int wv  = tid >> 6;
  const int ln  = tid & 63;

  u64* buf0 = (u64*)ws;        // {tag|val} pairs, even tags
  u64* buf1 = buf0 + H;        // odd tags

  __shared__ __align__(16) float h_lds[2][H];

  // h_0 = 0: zero parity-0 LDS row (512 threads x 16B)
  *(vf4*)&h_lds[0][4 * tid] = (vf4)(0.0f);

  // ---- persistent weights: load then pin ----
  const int j = b * 8 + wv;
  DECLG(0) DECLG(1) DECLG(2) DECLG(3)
  LOADG(0) LOADG(1) LOADG(2) LOADG(3)
  PIN(0) PIN(1) PIN(2) PIN(3)

  __syncthreads();

  float cst = 0.0f;

  #pragma unroll 1
  for (int t = 0; t < TSTEPS; ++t) {
    const vf2 xr = *(const vf2*)(x + (long)t * FEAT + 2 * ln);
    float* ldsrow = h_lds[t & 1];

    if (t > 0)
      stage_slice((t & 1) ? buf1 : buf0, (unsigned)t, ldsrow, wv, ln);
    __syncthreads();

    LDSREAD(0, ldsrow) LDSREAD(1, ldsrow) LDSREAD(2, ldsrow) LDSREAD(3, ldsrow)
    LDSREAD(4, ldsrow) LDSREAD(5, ldsrow) LDSREAD(6, ldsrow) LDSREAD(7, ldsrow)

    acc0 = wih0.x * xr.x + wih0.y * xr.y;
    acc1 = wih1.x * xr.x + wih1.y * xr.y;
    acc2 = wih2.x * xr.x + wih2.y * xr.y;
    acc3 = wih3.x * xr.x + wih3.y * xr.y;

    FMA_C(0) FMA_C(1) FMA_C(2) FMA_C(3)
    FMA_C(4) FMA_C(5) FMA_C(6) FMA_C(7)

    REDUCE(0) REDUCE(1) REDUCE(2) REDUCE(3)

    // gate order [i, f, g, o]
    const float iv = sigm(acc0);
    const float fv = sigm(acc1);
    const float gv = tanh_(acc2);
    const float ov = sigm(acc3);
    cst = fv * cst + iv * gv;
    const float hval = ov * tanh_(cst);

    if (ln == 0) {
      u64* dst = (((t + 1) & 1) ? buf1 : buf0) + j;
      const u64 pack = ((u64)__float_as_uint(hval) << 32)
                     | (unsigned)(t + 1);
      __hip_atomic_store(dst, pack, __ATOMIC_RELAXED,
                         __HIP_MEMORY_SCOPE_AGENT);
    }
    // no trailing barrier: next iteration's syncthreads joins waves; the
    // tag protocol provides all cross-block ordering.
  }

  // ---- head phase 1: ylin[j] = b_lin[j] + dot(W_lin[j,:], h_final) ----
  // h_final: tag TSTEPS (even) in buf0.
  {
    float* ldsrow = h_lds[0];
    stage_slice(buf0, (unsigned)TSTEPS, ldsrow, wv, ln);
    __syncthreads();

    float a0 = 0.0f;
    const float* wl = W_lin + (long)j * H;
    #pragma unroll
    for (int k = 0; k < 8; ++k) {
      const vf4 h4 = *(const vf4*)&ldsrow[4 * (ln + 64 * k)];
      const vf4 u  = *(const vf4*)(wl + 4 * (ln + 64 * k));
      a0 += u.x * h4.x + u.y * h4.y + u.z * h4.z + u.w * h4.w;
    }
    a0 += __shfl_xor(a0, 1);  a0 += __shfl_xor(a0, 2);  a0 += __shfl_xor(a0, 4);
    a0 += __shfl_xor(a0, 8);  a0 += __shfl_xor(a0, 16); a0 += __shfl_xor(a0, 32);

    if (ln == 0) {
      const float yv = a0 + b_lin[j];
      const u64 pack = ((u64)__float_as_uint(yv) << 32)
                     | (unsigned)(TSTEPS + 1);
      __hip_atomic_store(buf1 + j, pack, __ATOMIC_RELAXED,
                         __HIP_MEMORY_SCOPE_AGENT);
    }
  }

  // ---- head phase 2: y = ylin @ W_out.T + b_out (block 0, wave 0) ----
  if (b == 0 && wv == 0) {
    u64 pv[32];
    #pragma unroll
    for (int k = 0; k < 32; ++k)
      pv[k] = aload(buf1 + ln + 64 * k);
    while (true) {
      int ok = 1;
      #pragma unroll
      for (int k = 0; k < 32; ++k)
        ok &= ((unsigned)pv[k] == (unsigned)(TSTEPS + 1)) ? 1 : 0;
      if (__all(ok)) break;
      __builtin_amdgcn_s_sleep(1);
      #pragma unroll
      for (int k = 0; k < 32; ++k)
        if ((unsigned)pv[k] != (unsigned)(TSTEPS + 1))
          pv[k] = aload(buf1 + ln + 64 * k);
    }
    float p0 = 0.0f, p1 = 0.0f;
    #pragma unroll
    for (int k = 0; k < 32; ++k) {
      const int c = ln + 64 * k;
      const float yv = __uint_as_float((unsigned)(pv[k] >> 32));
      p0 = __builtin_fmaf(W_out[c],     yv, p0);
      p1 = __builtin_fmaf(W_out[H + c], yv, p1);
    }
    p0 += __shfl_xor(p0, 1);  p0 += __shfl_xor(p0, 2);  p0 += __shfl_xor(p0, 4);
    p0 += __shfl_xor(p0, 8);  p0 += __shfl_xor(p0, 16); p0 += __shfl_xor(p0, 32);
    p1 += __shfl_xor(p1, 1);  p1 += __shfl_xor(p1, 2);  p1 += __shfl_xor(p1, 4);
    p1 += __shfl_xor(p1, 8);  p1 += __shfl_xor(p1, 16); p1 += __shfl_xor(p1, 32);
    if (ln == 0) {
      out[0] = p0 + b_out[0];
      out[1] = p1 + b_out[1];
    }
  }
}

extern "C" void kernel_launch(void* const* d_in, const int* in_sizes, int n_in,
                              void* d_out, int out_size, void* d_ws, size_t ws_size,
                              hipStream_t stream) {
  const float* x     = (const float*)d_in[0];
  const float* W_ih  = (const float*)d_in[1];
  const float* W_hh  = (const float*)d_in[2];
  const float* b_ih  = (const float*)d_in[3];
  const float* b_hh  = (const float*)d_in[4];
  const float* W_lin = (const float*)d_in[5];
  const float* b_lin = (const float*)d_in[6];
  const float* W_out = (const float*)d_in[7];
  const float* b_out = (const float*)d_in[8];

  lstm_persist<<<dim3(NBLK), dim3(NTHR), 0, stream>>>(
      x, W_ih, W_hh, b_ih, b_hh, W_lin, b_lin, W_out, b_out,
      (float*)d_out, (float*)d_ws);
}

// Round 6
// 34404.175 us; speedup vs baseline: 1.9248x; 1.3354x over previous
//
#include <hip/hip_runtime.h>

// Persistent-LSTM MI355X — Round 6: compact per-block tag counters.
// R3/R4/R5 all cost 4.5-5.6us/step on sync; compute is only ~0.25us.
// Diagnosis: consumers polled the full 256-line data region (R4/R5: FETCH
// 2GB poll storm + per-wave straggler tails) or serialized 32 RMWs/line (R3).
// R6: block b publishes plain h values (sc1), __syncthreads drains vmcnt
// (data visible — the R3-validated ordering), then tid0 STORES slot[b]=t+1
// (no RMW). All 256 slots = 1KB = 16 lines. Wave wv polls only its slice's
// 2 tag lines (32 slots, 1 load/lane), then one-shot reads its 2KB h-slice.
// Poll traffic /16, no atomic-unit serialization, no reset phase (0xAA
// poison is negative as int32 -> signed compare makes it inert).
//
// 256 blocks x 512 threads, 1 block/CU (measured 8 waves/CU in R3-R5) ->
// all blocks co-resident -> spin-poll deadlock-free (slots are monotonic).
// Block b owns units [8b,8b+8); wave wv computes unit j=8b+wv; lane ln owns
// h-chunks {ln+64k} for FMA and contiguous 4 floats for staging.

#define H      2048
#define TSTEPS 8192
#define FEAT   128
#define NBLK   256
#define NTHR   512

typedef float vf4 __attribute__((ext_vector_type(4)));
typedef float vf2 __attribute__((ext_vector_type(2)));
typedef unsigned long long u64;
typedef unsigned int u32;

__device__ __forceinline__ float sigm(float xv) {
  return __builtin_amdgcn_rcpf(1.0f + __expf(-xv));
}
__device__ __forceinline__ float tanh_(float xv) {
  return 1.0f - 2.0f * __builtin_amdgcn_rcpf(__expf(2.0f * xv) + 1.0f);
}

__device__ __forceinline__ u64 aload64(const u64* p) {
  return __hip_atomic_load(p, __ATOMIC_RELAXED, __HIP_MEMORY_SCOPE_AGENT);
}
__device__ __forceinline__ u32 aload32(const u32* p) {
  return __hip_atomic_load(p, __ATOMIC_RELAXED, __HIP_MEMORY_SCOPE_AGENT);
}
__device__ __forceinline__ void astoref(float* p, float v) {
  __hip_atomic_store(p, v, __ATOMIC_RELAXED, __HIP_MEMORY_SCOPE_AGENT);
}
__device__ __forceinline__ void astoreu(u32* p, u32 v) {
  __hip_atomic_store(p, v, __ATOMIC_RELAXED, __HIP_MEMORY_SCOPE_AGENT);
}

#define DECLG(g) vf4 w##g##_0, w##g##_1, w##g##_2, w##g##_3, \
                     w##g##_4, w##g##_5, w##g##_6, w##g##_7; \
                 vf2 wih##g; float bias##g; float acc##g;

#define LOADG(g) { \
  const int row_ = (g) * H + j; \
  const float* wr_ = W_hh + (long)row_ * H; \
  w##g##_0 = *(const vf4*)(wr_ + 4*(ln      )); \
  w##g##_1 = *(const vf4*)(wr_ + 4*(ln +  64)); \
  w##g##_2 = *(const vf4*)(wr_ + 4*(ln + 128)); \
  w##g##_3 = *(const vf4*)(wr_ + 4*(ln + 192)); \
  w##g##_4 = *(const vf4*)(wr_ + 4*(ln + 256)); \
  w##g##_5 = *(const vf4*)(wr_ + 4*(ln + 320)); \
  w##g##_6 = *(const vf4*)(wr_ + 4*(ln + 384)); \
  w##g##_7 = *(const vf4*)(wr_ + 4*(ln + 448)); \
  wih##g  = *(const vf2*)(W_ih + (long)row_ * FEAT + 2*ln); \
  bias##g = b_ih[row_] + b_hh[row_]; }

// Opaque pin: weights become non-rematerializable (cannot re-sink into loop).
#define PIN(g) asm volatile("" : \
  "+v"(w##g##_0), "+v"(w##g##_1), "+v"(w##g##_2), "+v"(w##g##_3), \
  "+v"(w##g##_4), "+v"(w##g##_5), "+v"(w##g##_6), "+v"(w##g##_7), \
  "+v"(wih##g), "+v"(bias##g));

#define LDSREAD(k, ldsrow) \
  const vf4 hv##k = *(const vf4*)&(ldsrow)[4*(ln + 64*(k))];

#define FMA_G(g, c) \
  acc##g = __builtin_fmaf(w##g##_##c.x, h4_.x, acc##g); \
  acc##g = __builtin_fmaf(w##g##_##c.y, h4_.y, acc##g); \
  acc##g = __builtin_fmaf(w##g##_##c.z, h4_.z, acc##g); \
  acc##g = __builtin_fmaf(w##g##_##c.w, h4_.w, acc##g);

#define FMA_C(c) { const vf4 h4_ = hv##c; \
  FMA_G(0, c) FMA_G(1, c) FMA_G(2, c) FMA_G(3, c) }

#define REDUCE(g) { float a_ = acc##g; \
  a_ += __shfl_xor(a_, 1);  a_ += __shfl_xor(a_, 2);  a_ += __shfl_xor(a_, 4); \
  a_ += __shfl_xor(a_, 8);  a_ += __shfl_xor(a_, 16); a_ += __shfl_xor(a_, 32); \
  acc##g = a_ + bias##g; }

// Wave wv: (1) poll the 32 slot-counters of its slice's producer blocks
// (2 cache lines; lanes 0..31, one u32 each) until all >= tgt (signed: 0xAA
// poison is negative -> inert); (2) one-shot read its 256-float h-slice
// (4 floats/lane via 2 u64 sc1 loads); (3) deposit into LDS.
__device__ __forceinline__ void poll_and_stage(const u32* __restrict__ slots,
                                               const float* __restrict__ hsrc,
                                               int tgt,
                                               float* __restrict__ ldsrow,
                                               int wv, int ln) {
  const u32* sp = slots + wv * 32 + (ln & 31);
  int v = (int)aload32(sp);
  while (!__all((ln < 32) ? (v >= tgt) : 1)) {
    __builtin_amdgcn_s_sleep(1);
    if ((ln < 32) && (v < tgt)) v = (int)aload32(sp);
  }
  const int base = wv * 256 + 4 * ln;
  const u64* hp = (const u64*)(hsrc + base);
  const u64 d0 = aload64(hp);
  const u64 d1 = aload64(hp + 1);
  vf4 hv;
  hv.x = __uint_as_float((u32)d0);
  hv.y = __uint_as_float((u32)(d0 >> 32));
  hv.z = __uint_as_float((u32)d1);
  hv.w = __uint_as_float((u32)(d1 >> 32));
  *(vf4*)&ldsrow[base] = hv;
}

__global__ __launch_bounds__(NTHR, 2)
void lstm_persist(const float* __restrict__ x,
                  const float* __restrict__ W_ih,
                  const float* __restrict__ W_hh,
                  const float* __restrict__ b_ih,
                  const float* __restrict__ b_hh,
                  const float* __restrict__ W_lin,
                  const float* __restrict__ b_lin,
                  const float* __restrict__ W_out,
                  const float* __restrict__ b_out,
                  float* __restrict__ out,
                  float* __restrict__ ws)
{
  const int tid = threadIdx.x;
  const int b   = blockIdx.x;
  const int wv  = tid >> 6;
  const int ln  = tid & 63;

  float* hbuf0 = ws;            // [2048] h for even t
  float* hbuf1 = ws + H;        // [2048] h for odd t; reused for ylin
  u32*   slots = (u32*)(ws + 2 * H);   // [256] per-block step counters, 1KB

  __shared__ __align__(16) float h_lds[2][H];

  // h_0 = 0: zero parity-0 LDS row (512 threads x 16B)
  *(vf4*)&h_lds[0][4 * tid] = (vf4)(0.0f);

  // ---- persistent weights: load then pin ----
  const int j = b * 8 + wv;
  DECLG(0) DECLG(1) DECLG(2) DECLG(3)
  LOADG(0) LOADG(1) LOADG(2) LOADG(3)
  PIN(0) PIN(1) PIN(2) PIN(3)

  __syncthreads();

  float cst = 0.0f;

  #pragma unroll 1
  for (int t = 0; t < TSTEPS; ++t) {
    const vf2 xr = *(const vf2*)(x + (long)t * FEAT + 2 * ln);
    float* ldsrow = h_lds[t & 1];

    if (t > 0)
      poll_and_stage(slots, (t & 1) ? hbuf1 : hbuf0, t, ldsrow, wv, ln);
    __syncthreads();

    LDSREAD(0, ldsrow) LDSREAD(1, ldsrow) LDSREAD(2, ldsrow) LDSREAD(3, ldsrow)
    LDSREAD(4, ldsrow) LDSREAD(5, ldsrow) LDSREAD(6, ldsrow) LDSREAD(7, ldsrow)

    acc0 = wih0.x * xr.x + wih0.y * xr.y;
    acc1 = wih1.x * xr.x + wih1.y * xr.y;
    acc2 = wih2.x * xr.x + wih2.y * xr.y;
    acc3 = wih3.x * xr.x + wih3.y * xr.y;

    FMA_C(0) FMA_C(1) FMA_C(2) FMA_C(3)
    FMA_C(4) FMA_C(5) FMA_C(6) FMA_C(7)

    REDUCE(0) REDUCE(1) REDUCE(2) REDUCE(3)

    // gate order [i, f, g, o]
    const float iv = sigm(acc0);
    const float fv = sigm(acc1);
    const float gv = tanh_(acc2);
    const float ov = sigm(acc3);
    cst = fv * cst + iv * gv;
    const float hval = ov * tanh_(cst);

    // publish h_{t+1}: 8 plain sc1 stores per block (one line)
    if (ln == 0)
      astoref((((t + 1) & 1) ? hbuf1 : hbuf0) + j, hval);

    // syncthreads drains vmcnt(0) per wave before s_barrier -> all 8 h
    // stores of this block are visible BEFORE the tag store below.
    __syncthreads();
    if (tid == 0)
      astoreu(slots + b, (u32)(t + 1));
  }

  // ---- head phase 1: ylin[j] = b_lin[j] + dot(W_lin[j,:], h_final) ----
  // h_final = h_8192, parity 0; all slots reach TSTEPS after the loop.
  {
    float* ldsrow = h_lds[0];
    poll_and_stage(slots, hbuf0, TSTEPS, ldsrow, wv, ln);
    __syncthreads();

    float a0 = 0.0f;
    const float* wl = W_lin + (long)j * H;
    #pragma unroll
    for (int k = 0; k < 8; ++k) {
      const vf4 h4 = *(const vf4*)&ldsrow[4 * (ln + 64 * k)];
      const vf4 u  = *(const vf4*)(wl + 4 * (ln + 64 * k));
      a0 += u.x * h4.x + u.y * h4.y + u.z * h4.z + u.w * h4.w;
    }
    a0 += __shfl_xor(a0, 1);  a0 += __shfl_xor(a0, 2);  a0 += __shfl_xor(a0, 4);
    a0 += __shfl_xor(a0, 8);  a0 += __shfl_xor(a0, 16); a0 += __shfl_xor(a0, 32);

    if (ln == 0)
      astoref(hbuf1 + j, a0 + b_lin[j]);   // ylin lives in hbuf1 (safe: all
                                           // blocks are past reading h_8191)
    __syncthreads();
    if (tid == 0)
      astoreu(slots + b, (u32)(TSTEPS + 1));
  }

  // ---- head phase 2: y = ylin @ W_out.T + b_out (block 0, wave 0) ----
  if (b == 0 && wv == 0) {
    // poll all 256 slots: lane ln covers slots 4ln..4ln+3
    const u32* sp = slots + 4 * ln;
    int v0 = (int)aload32(sp + 0), v1 = (int)aload32(sp + 1);
    int v2 = (int)aload32(sp + 2), v3 = (int)aload32(sp + 3);
    const int tgt = TSTEPS + 1;
    while (!__all((v0 >= tgt) & (v1 >= tgt) & (v2 >= tgt) & (v3 >= tgt))) {
      __builtin_amdgcn_s_sleep(1);
      if (v0 < tgt) v0 = (int)aload32(sp + 0);
      if (v1 < tgt) v1 = (int)aload32(sp + 1);
      if (v2 < tgt) v2 = (int)aload32(sp + 2);
      if (v3 < tgt) v3 = (int)aload32(sp + 3);
    }
    float p0 = 0.0f, p1 = 0.0f;
    #pragma unroll
    for (int k = 0; k < 16; ++k) {
      const u64 d  = aload64((const u64*)hbuf1 + ln + 64 * k);
      const int c  = 2 * (ln + 64 * k);
      const float ylo = __uint_as_float((u32)d);
      const float yhi = __uint_as_float((u32)(d >> 32));
      p0 = __builtin_fmaf(W_out[c],         ylo, p0);
      p0 = __builtin_fmaf(W_out[c + 1],     yhi, p0);
      p1 = __builtin_fmaf(W_out[H + c],     ylo, p1);
      p1 = __builtin_fmaf(W_out[H + c + 1], yhi, p1);
    }
    p0 += __shfl_xor(p0, 1);  p0 += __shfl_xor(p0, 2);  p0 += __shfl_xor(p0, 4);
    p0 += __shfl_xor(p0, 8);  p0 += __shfl_xor(p0, 16); p0 += __shfl_xor(p0, 32);
    p1 += __shfl_xor(p1, 1);  p1 += __shfl_xor(p1, 2);  p1 += __shfl_xor(p1, 4);
    p1 += __shfl_xor(p1, 8);  p1 += __shfl_xor(p1, 16); p1 += __shfl_xor(p1, 32);
    if (ln == 0) {
      out[0] = p0 + b_out[0];
      out[1] = p1 + b_out[1];
    }
  }
}

extern "C" void kernel_launch(void* const* d_in, const int* in_sizes, int n_in,
                              void* d_out, int out_size, void* d_ws, size_t ws_size,
                              hipStream_t stream) {
  const float* x     = (const float*)d_in[0];
  const float* W_ih  = (const float*)d_in[1];
  const float* W_hh  = (const float*)d_in[2];
  const float* b_ih  = (const float*)d_in[3];
  const float* b_hh  = (const float*)d_in[4];
  const float* W_lin = (const float*)d_in[5];
  const float* b_lin = (const float*)d_in[6];
  const float* W_out = (const float*)d_in[7];
  const float* b_out = (const float*)d_in[8];

  lstm_persist<<<dim3(NBLK), dim3(NTHR), 0, stream>>>(
      x, W_ih, W_hh, b_ih, b_hh, W_lin, b_lin, W_out, b_out,
      (float*)d_out, (float*)d_ws);
}